// Round 9
// baseline (140.805 us; speedup 1.0000x reference)
//
#include <hip/hip_runtime.h>
#include <math.h>

// L = 2*pi * log2(e): exp(-2pi r^2) == exp2(-L r^2)
#define LCONST 9.064720283654388f

// dom binned into 5x5x5 cells (size 2.0) over [0,10)^3; C1/C binned by (x,y)
// COLUMN only (25 columns). A cell's neighborhood = <=9 columns; the missing
// z-filter is free because out-of-cutoff pairs underflow exp2 to 0.
// Cutoff r=2: dropped terms ~1.2e-11 vs theta ~0.36 -> below f32 ulp: exact.
#define NC 5
#define NCELL 125
#define NCOL 25
#define DOMCAP 192   // dom/cell: mean 131, sigma 11.4 -> +5.3 sigma (r2-r8 passed)
#define COLCAP 96    // pts/(b,col): mean 41, sigma 6.4 -> +8.6 sigma
#define NB 16
#define MAIN_BLOCKS (NB * NCELL)  // 2000 blocks = one wave per (b,cell)
#define LCAP 576     // packed padded 9-col list: mean ~340, +9sigma ~475; x8
#define DUMMYW -1.0e30f  // pad w: arg <= -1e30 -> exp2 = 0 exactly, no NaN path

// cnts word layout (every word written unconditionally by k_setup -> NO memset)
#define W_CNTD 0      // 125
#define W_CNTC1 125   // 16*25 = 400
#define W_CNTC 525    // 25
#define W_PROD 550    // 16 floats
#define W_DONE 566    // block ticket
#define W_TOTAL 567

__device__ __forceinline__ float fexp2(float x) {
#if defined(__has_builtin)
#if __has_builtin(__builtin_amdgcn_exp2f)
    return __builtin_amdgcn_exp2f(x);
#else
    return exp2f(x);
#endif
#else
    return exp2f(x);
#endif
}

__device__ __forceinline__ int clamp5(float v) {
    int c = (int)(v * 0.5f);
    return c < 0 ? 0 : (c > NC - 1 ? NC - 1 : c);
}

// Full exponent arg = -L||d-q||^2 <= 0 stays in ONE exp2 argument (factoring
// exp2(d.w) out overflows: inf*0=NaN -- round-1 bug).
#define PAIR_ARG(d, q) fmaf((d).x, (q).x, fmaf((d).y, (q).y, fmaf((d).z, (q).z, (d).w + (q).w)))

// One q against the lane's THREE dom points (R=3 register tile): each 16B
// broadcast read now feeds 192 pair-evals, not 64 -- r8's counters showed
// k_main pinned at the ds_read_b128 throughput ceiling (13.2 cyc/read/CU).
#define EVAL3(qq) do { \
    s0 += fexp2(PAIR_ARG(d0, qq)); \
    s1 += fexp2(PAIR_ARG(d1, qq)); \
    s2 += fexp2(PAIR_ARG(d2, qq)); } while (0)

#define BODY8(P, I) do { \
    float4 q0 = (P)[(I)],     q1 = (P)[(I) + 1], q2 = (P)[(I) + 2], q3 = (P)[(I) + 3]; \
    float4 q4 = (P)[(I) + 4], q5 = (P)[(I) + 5], q6 = (P)[(I) + 6], q7 = (P)[(I) + 7]; \
    EVAL3(q0); EVAL3(q1); EVAL3(q2); EVAL3(q3); \
    EVAL3(q4); EVAL3(q5); EVAL3(q6); EVAL3(q7); } while (0)

// Node 1: all binning with LDS-LOCAL counters (no global counters to pre-zero
// -> the memset node is deleted; every cnts word is written unconditionally).
// blocks 0-15: C1[b]; block 16: C + zero prod/ticket; block 17: dom.
// Also pads every column list to x8 with DUMMYW so scans are remainder-free.
__global__ void __launch_bounds__(1024) k_setup(const float* __restrict__ C1,
                                                const float* __restrict__ C,
                                                const float* __restrict__ dom,
                                                float4* __restrict__ PDbin,
                                                float4* __restrict__ C1col,
                                                float4* __restrict__ Ccol,
                                                int* __restrict__ cnts) {
    int* cntD  = cnts + W_CNTD;
    int* cntC1 = cnts + W_CNTC1;
    int* cntC  = cnts + W_CNTC;
    float* prod = (float*)(cnts + W_PROD);
    unsigned* done = (unsigned*)(cnts + W_DONE);
    __shared__ int pos[NCELL];
    int t = threadIdx.x, blk = blockIdx.x;

    if (blk < 16) {                      // ---- C1[b]: 1024 pts, 1/thread ----
        if (t < NCOL) pos[t] = 0;
        __syncthreads();
        int j = (blk << 10) + t;
        float x = C1[3 * j], y = C1[3 * j + 1], z = C1[3 * j + 2];
        int col = clamp5(x) * NC + clamp5(y);
        int s = atomicAdd(&pos[col], 1);         // LDS atomic (block-local)
        if (s < COLCAP)                          // clamp: overflow can't OOB
            C1col[(blk * NCOL + col) * COLCAP + s] =
                make_float4(x, y, z, -LCONST * (x * x + y * y + z * z));
        __syncthreads();
        if (t < NCOL) cntC1[blk * NCOL + t] = min(pos[t], COLCAP);
        if (t < NCOL * 8) {                      // pad to x8 with exp2->0 dummies
            int c2 = t >> 3, k = t & 7;
            int c = min(pos[c2], COLCAP), n8 = (c + 7) & ~7;
            if (c + k < n8)
                C1col[(blk * NCOL + c2) * COLCAP + c + k] =
                    make_float4(0.f, 0.f, 0.f, DUMMYW);
        }
    } else if (blk == 16) {              // ---- C + zero prod/ticket ----
        if (t < NCOL) pos[t] = 0;
        __syncthreads();
        float x = C[3 * t], y = C[3 * t + 1], z = C[3 * t + 2];
        int col = clamp5(x) * NC + clamp5(y);
        int s = atomicAdd(&pos[col], 1);
        if (s < COLCAP)
            Ccol[col * COLCAP + s] =
                make_float4(x, y, z, -LCONST * (x * x + y * y + z * z));
        __syncthreads();
        if (t < NCOL) cntC[t] = min(pos[t], COLCAP);
        if (t < NCOL * 8) {
            int c2 = t >> 3, k = t & 7;
            int c = min(pos[c2], COLCAP), n8 = (c + 7) & ~7;
            if (c + k < n8)
                Ccol[c2 * COLCAP + c + k] = make_float4(0.f, 0.f, 0.f, DUMMYW);
        }
        if (t >= 512 && t < 528) prod[t - 512] = 0.0f;
        if (t == 528) *done = 0u;
    } else {                             // ---- dom: 16384 pts, 16 iters ----
        if (t < NCELL) pos[t] = 0;
        __syncthreads();
        #pragma unroll 1
        for (int it = 0; it < 16; ++it) {
            int j = (it << 10) + t;
            float x = dom[3 * j], y = dom[3 * j + 1], z = dom[3 * j + 2];
            int cell = (clamp5(x) * NC + clamp5(y)) * NC + clamp5(z);
            int s = atomicAdd(&pos[cell], 1);
            if (s < DOMCAP)
                PDbin[cell * DOMCAP + s] =
                    make_float4(2.f * LCONST * x, 2.f * LCONST * y, 2.f * LCONST * z,
                                -LCONST * (x * x + y * y + z * z));
        }
        __syncthreads();
        if (t < NCELL) cntD[t] = min(pos[t], DOMCAP);
    }
}

// Node 2: one wave per (b,cell). Lane holds d0,d1,d2 (R=3). theta_b: stage
// padded 9-col list into LDS once, scan with 1 broadcast ds_read per 192
// pair-evals. theta_C: scan Ccol DIRECTLY via wave-uniform scalar loads
// (38KB, K$/L1-hot, separate pipe -- off the LDS unit entirely).
// Tail: one atomic per block + vmcnt-ordered ticket (r7/r8 proven).
__global__ void __launch_bounds__(64) k_main(const float4* __restrict__ PDbin,
                                             const float4* __restrict__ C1col,
                                             const float4* __restrict__ Ccol,
                                             int* __restrict__ cnts,
                                             float* __restrict__ out) {
    const int* cntD  = cnts + W_CNTD;
    const int* cntC1 = cnts + W_CNTC1;
    const int* cntC  = cnts + W_CNTC;
    float* prod = (float*)(cnts + W_PROD);
    unsigned* done = (unsigned*)(cnts + W_DONE);

    __shared__ float4 slB[LCAP];
    int lane = threadIdx.x;
    int b = blockIdx.x / NCELL, cell = blockIdx.x - b * NCELL;
    int cx = cell / 25, cy = (cell / 5) % 5;
    int xlo = cx > 0 ? cx - 1 : 0, xhi = cx < NC - 1 ? cx + 1 : NC - 1;
    int ylo = cy > 0 ? cy - 1 : 0, yhi = cy < NC - 1 ? cy + 1 : NC - 1;

    // ---- stage theta_b list (already x8-padded in global) into LDS ----
    int off = 0;
    #pragma unroll 1
    for (int x2 = xlo; x2 <= xhi; ++x2) {
        #pragma unroll 1
        for (int y2 = ylo; y2 <= yhi; ++y2) {
            int col = x2 * NC + y2;
            int n8 = (min(cntC1[b * NCOL + col], COLCAP) + 7) & ~7;
            if (off + n8 > LCAP) n8 = LCAP - off;   // drop-clamp, never OOB (x8 kept)
            const float4* __restrict__ src = C1col + (size_t)(b * NCOL + col) * COLCAP;
            if (lane < n8) slB[off + lane] = src[lane];
            if (lane + 64 < n8) slB[off + lane + 64] = src[lane + 64];
            off += n8;
        }
    }
    int nB8 = off;                                  // multiple of 8

    // ---- R=3 dom register tile (sanitize dead lanes) ----
    int len = cntD[cell];                           // uniform scalar
    const float4* __restrict__ PD = PDbin + cell * DOMCAP;
    float4 d0 = make_float4(0.f, 0.f, 0.f, 0.f);
    float4 d1 = d0, d2 = d0;
    if (lane < len)       d0 = PD[lane];
    if (lane + 64 < len)  d1 = PD[lane + 64];
    if (lane + 128 < len) d2 = PD[lane + 128];
    __syncthreads();

    // ---- theta_b scan (LDS broadcast, remainder-free) ----
    float s0 = 0.f, s1 = 0.f, s2 = 0.f;
    #pragma unroll 1
    for (int i = 0; i < nB8; i += 8) BODY8(slB, i);
    float accb0 = s0, accb1 = s1, accb2 = s2;

    // ---- theta_C scan (global wave-uniform, K$-resident, remainder-free) ----
    s0 = 0.f; s1 = 0.f; s2 = 0.f;
    #pragma unroll 1
    for (int x2 = xlo; x2 <= xhi; ++x2) {
        #pragma unroll 1
        for (int y2 = ylo; y2 <= yhi; ++y2) {
            int col = x2 * NC + y2;
            int n8 = (min(cntC[col], COLCAP) + 7) & ~7;
            const float4* __restrict__ p = Ccol + col * COLCAP;
            #pragma unroll 1
            for (int i = 0; i < n8; i += 8) BODY8(p, i);
        }
    }

    // ---- combine, reduce, accumulate, ticket-finalize ----
    float v = ((lane < len) ? accb0 * s0 : 0.f)
            + ((lane + 64 < len) ? accb1 * s1 : 0.f)
            + ((lane + 128 < len) ? accb2 * s2 : 0.f);   // select: NaN-safe
    for (int o = 32; o; o >>= 1) v += __shfl_down(v, o, 64);
    unsigned old = 0;
    if (lane == 0) {
        atomicAdd(prod + b, v);
        asm volatile("s_waitcnt vmcnt(0)" ::: "memory");  // prod add performed
        old = atomicAdd(done, 1u);
    }
    old = __shfl(old, 0, 64);
    if (old == (unsigned)(MAIN_BLOCKS - 1) && lane < 16) {
        const float scale = 4.76837158203125e-4f;  // A*V/1024
        float p = atomicAdd(prod + lane, 0.0f);    // coherent read
        float dot = fminf(fmaxf(p * scale, 0.0f), 1.0f);
        out[lane] = 1.0f - dot;
    }
}

extern "C" void kernel_launch(void* const* d_in, const int* in_sizes, int n_in,
                              void* d_out, int out_size, void* d_ws, size_t ws_size,
                              hipStream_t stream) {
    const float* C1  = (const float*)d_in[0];   // (16,1024,3)
    const float* C   = (const float*)d_in[1];   // (1024,3)
    const float* dom = (const float*)d_in[2];   // (16384,3)
    float* out = (float*)d_out;                 // (16,)

    char* ws = (char*)d_ws;
    float4* PDbin = (float4*)(ws + 0);          // 125*192*16   =  384000
    float4* C1col = (float4*)(ws + 384000);     // 16*25*96*16  =  614400 ->  998400
    float4* Ccol  = (float4*)(ws + 998400);     // 25*96*16     =   38400 -> 1036800
    int*    cnts  = (int*)(ws + 1036800);       // 567 words    -> ~1.04MB total

    k_setup<<<18, 1024, 0, stream>>>(C1, C, dom, PDbin, C1col, Ccol, cnts);
    k_main<<<MAIN_BLOCKS, 64, 0, stream>>>(PDbin, C1col, Ccol, cnts, out);
}

// Round 10
// 135.330 us; speedup vs baseline: 1.0405x; 1.0405x over previous
//
#include <hip/hip_runtime.h>
#include <math.h>

// L = 2*pi * log2(e): exp(-2pi r^2) == exp2(-L r^2)
#define LCONST 9.064720283654388f

// dom binned into 5x5x5 cells (size 2.0) over [0,10)^3; C1/C binned by (x,y)
// COLUMN only (25 columns). A cell's neighborhood = <=9 columns; the missing
// z-filter is free because out-of-cutoff pairs underflow exp2 to 0.
// Cutoff r=2: dropped terms ~1.2e-11 vs theta ~0.36 -> below f32 ulp: exact.
#define NC 5
#define NCELL 125
#define NCOL 25
#define DOMCAP 192   // dom/cell: mean 131, sigma 11.4 -> +5.3 sigma (r2-r9 passed)
#define COLCAP 96    // pts/(b,col): mean 41, sigma 6.4 -> +8.6 sigma
#define NB 16
#define GRID_BIN 132              // 132*256 = 33792 = exactly all points to bin
#define MAIN_BLOCKS (NB * NCELL)  // 2000 blocks, 4 waves each = 8000 waves
#define LCAP 576     // concat nbhd list cap: mean 277, +9sigma ~475; mult of 8
#define DUMMYW -1.0e30f  // pad w: arg <= -1e30 -> exp2 = 0 exactly, no NaN path

// cnts word layout (memset-zeroed each run)
#define W_CNTD 0      // 125
#define W_CNTC1 125   // 400
#define W_CNTC 525    // 25
#define W_NQCL 550    // 400: padded concat-list lengths per (b,nbhd)
#define W_PROD 950    // 16 floats
#define W_DONE 966    // block ticket
#define W_TOTAL 967

__device__ __forceinline__ float fexp2(float x) {
#if defined(__has_builtin)
#if __has_builtin(__builtin_amdgcn_exp2f)
    return __builtin_amdgcn_exp2f(x);
#else
    return exp2f(x);
#endif
#else
    return exp2f(x);
#endif
}

__device__ __forceinline__ int clamp5(float v) {
    int c = (int)(v * 0.5f);
    return c < 0 ? 0 : (c > NC - 1 ? NC - 1 : c);
}

// Full exponent arg = -L||d-q||^2 <= 0 stays in ONE exp2 argument (factoring
// exp2(d.w) out overflows: inf*0=NaN -- round-1 bug).
#define PAIR_ARG(d, q) fmaf((d).x, (q).x, fmaf((d).y, (q).y, fmaf((d).z, (q).z, (d).w + (q).w)))

// R=3 register tile: one q feeds the lane's 3 dom points (192 pairs/wave-q).
#define EVAL3(qq) do { \
    s0 += fexp2(PAIR_ARG(d0, qq)); \
    s1 += fexp2(PAIR_ARG(d1, qq)); \
    s2 += fexp2(PAIR_ARG(d2, qq)); } while (0)

#define BODY8(P, I) do { \
    float4 q0 = (P)[(I)],     q1 = (P)[(I) + 1], q2 = (P)[(I) + 2], q3 = (P)[(I) + 3]; \
    float4 q4 = (P)[(I) + 4], q5 = (P)[(I) + 5], q6 = (P)[(I) + 6], q7 = (P)[(I) + 7]; \
    EVAL3(q0); EVAL3(q1); EVAL3(q2); EVAL3(q3); \
    EVAL3(q4); EVAL3(q5); EVAL3(q6); EVAL3(q7); } while (0)

// R=1 tail-masked scan over the <=9 unpadded C columns (r7-proven tail:
// clamped loads never touch poisoned slots, selects mask dup contributions).
__device__ __forceinline__ float scan9(float4 d, int cx, int cy,
                                       const float4* __restrict__ cols,
                                       const int* __restrict__ cnt) {
    float a0 = 0.f, a1 = 0.f, a2 = 0.f, a3 = 0.f;
    int xlo = cx > 0 ? cx - 1 : 0, xhi = cx < NC - 1 ? cx + 1 : NC - 1;
    int ylo = cy > 0 ? cy - 1 : 0, yhi = cy < NC - 1 ? cy + 1 : NC - 1;
    #pragma unroll 1
    for (int x2 = xlo; x2 <= xhi; ++x2) {
        #pragma unroll 1
        for (int y2 = ylo; y2 <= yhi; ++y2) {
            int col = x2 * NC + y2;
            int n = __builtin_amdgcn_readfirstlane(min(cnt[col], COLCAP));
            if (n == 0) continue;
            const float4* __restrict__ p = cols + col * COLCAP;
            int nfull = n & ~7;
            int i = 0;
            #pragma unroll 1
            for (; i < nfull; i += 8) {
                float4 q0 = p[i],     q1 = p[i + 1], q2 = p[i + 2], q3 = p[i + 3];
                float4 q4 = p[i + 4], q5 = p[i + 5], q6 = p[i + 6], q7 = p[i + 7];
                a0 += fexp2(PAIR_ARG(d, q0)); a1 += fexp2(PAIR_ARG(d, q1));
                a2 += fexp2(PAIR_ARG(d, q2)); a3 += fexp2(PAIR_ARG(d, q3));
                a0 += fexp2(PAIR_ARG(d, q4)); a1 += fexp2(PAIR_ARG(d, q5));
                a2 += fexp2(PAIR_ARG(d, q6)); a3 += fexp2(PAIR_ARG(d, q7));
            }
            if (i < n) {
                int m = n - 1;
                float4 q0 = p[i];
                float4 q1 = p[min(i + 1, m)], q2 = p[min(i + 2, m)];
                float4 q3 = p[min(i + 3, m)], q4 = p[min(i + 4, m)];
                float4 q5 = p[min(i + 5, m)], q6 = p[min(i + 6, m)];
                float4 q7 = p[min(i + 7, m)];
                a0 += fexp2(PAIR_ARG(d, q0));
                a1 += (i + 1 < n) ? fexp2(PAIR_ARG(d, q1)) : 0.f;
                a2 += (i + 2 < n) ? fexp2(PAIR_ARG(d, q2)) : 0.f;
                a3 += (i + 3 < n) ? fexp2(PAIR_ARG(d, q3)) : 0.f;
                a0 += (i + 4 < n) ? fexp2(PAIR_ARG(d, q4)) : 0.f;
                a1 += (i + 5 < n) ? fexp2(PAIR_ARG(d, q5)) : 0.f;
                a2 += (i + 6 < n) ? fexp2(PAIR_ARG(d, q6)) : 0.f;
                a3 += (i + 7 < n) ? fexp2(PAIR_ARG(d, q7)) : 0.f;
            }
        }
    }
    return (a0 + a1) + (a2 + a3);
}

// Node 2: pure binning, global atomics, no fences (r7-proven).
__global__ void __launch_bounds__(256) k_bin(const float* __restrict__ C1,
                                             const float* __restrict__ C,
                                             const float* __restrict__ dom,
                                             float4* __restrict__ PDbin,
                                             float4* __restrict__ C1col,
                                             float4* __restrict__ Ccol,
                                             int* __restrict__ cnts) {
    int* cntD  = cnts + W_CNTD;
    int* cntC1 = cnts + W_CNTC1;
    int* cntC  = cnts + W_CNTC;
    int t = blockIdx.x * 256 + threadIdx.x;   // 0..33791 exactly
    if (t < 16384) {
        float x = dom[3 * t], y = dom[3 * t + 1], z = dom[3 * t + 2];
        int cell = (clamp5(x) * NC + clamp5(y)) * NC + clamp5(z);
        int s = atomicAdd(cntD + cell, 1);
        if (s < DOMCAP)   // clamp: overflowed bins can't OOB
            PDbin[cell * DOMCAP + s] =
                make_float4(2.0f * LCONST * x, 2.0f * LCONST * y, 2.0f * LCONST * z,
                            -LCONST * (x * x + y * y + z * z));
    } else if (t < 32768) {
        int j = t - 16384;
        float x = C1[3 * j], y = C1[3 * j + 1], z = C1[3 * j + 2];
        int b = j >> 10;
        int col = clamp5(x) * NC + clamp5(y);
        int s = atomicAdd(cntC1 + b * NCOL + col, 1);
        if (s < COLCAP)
            C1col[(b * NCOL + col) * COLCAP + s] =
                make_float4(x, y, z, -LCONST * (x * x + y * y + z * z));
    } else {
        int j = t - 32768;
        float x = C[3 * j], y = C[3 * j + 1], z = C[3 * j + 2];
        int col = clamp5(x) * NC + clamp5(y);
        int s = atomicAdd(cntC + col, 1);
        if (s < COLCAP)
            Ccol[col * COLCAP + s] =
                make_float4(x, y, z, -LCONST * (x * x + y * y + z * z));
    }
}

// Node 3: blocks 0-374 compute TC[slot] (theta_C once per dom slot -- kills
// r9's 16x redundant theta_C); blocks 375-774 concatenate each (b,nbhd)'s
// <=9 columns into ONE contiguous x8-padded global list (so k_main has no
// segments, no staging -- r7's segmentation and r8's LDS ceiling both gone).
__global__ void __launch_bounds__(64) k_tc(const float4* __restrict__ PDbin,
                                           const float4* __restrict__ C1col,
                                           const float4* __restrict__ Ccol,
                                           float4* __restrict__ CL,
                                           float* __restrict__ TC,
                                           int* __restrict__ cnts) {
    const int* cntD  = cnts + W_CNTD;
    const int* cntC1 = cnts + W_CNTC1;
    const int* cntC  = cnts + W_CNTC;
    int* nqCL = cnts + W_NQCL;
    int lane = threadIdx.x;
    int blk = blockIdx.x;

    if (blk < 375) {                    // ---- TC per (cell, chunk) ----
        int cell = blk / 3, chunk = blk - (blk / 3) * 3;
        int len = __builtin_amdgcn_readfirstlane(min(cntD[cell], DOMCAP));
        int slot = cell * DOMCAP + chunk * 64 + lane;
        if (chunk * 64 >= len) { TC[slot] = 0.f; return; }   // wave-uniform
        float4 d = make_float4(0.f, 0.f, 0.f, 0.f);          // sanitize poison
        if (chunk * 64 + lane < len) d = PDbin[slot];
        TC[slot] = scan9(d, cell / 25, (cell / 5) % 5, Ccol, cntC);
    } else {                            // ---- concat builder per (b, nbhd) ----
        int u = blk - 375;              // 0..399
        int b = u / NCOL, nbhd = u - b * NCOL;
        int cx = nbhd / NC, cy = nbhd - cx * NC;
        int xlo = cx > 0 ? cx - 1 : 0, xhi = cx < NC - 1 ? cx + 1 : NC - 1;
        int ylo = cy > 0 ? cy - 1 : 0, yhi = cy < NC - 1 ? cy + 1 : NC - 1;
        float4* __restrict__ dst = CL + (size_t)u * LCAP;
        int off = 0;
        for (int x2 = xlo; x2 <= xhi; ++x2) {
            for (int y2 = ylo; y2 <= yhi; ++y2) {
                int col = x2 * NC + y2;
                int n = __builtin_amdgcn_readfirstlane(min(cntC1[b * NCOL + col], COLCAP));
                const float4* __restrict__ src = C1col + (size_t)(b * NCOL + col) * COLCAP;
                for (int i = lane; i < n; i += 64)
                    if (off + i < LCAP) dst[off + i] = src[i];   // clamp: no OOB
                off += n;
            }
        }
        if (off > LCAP) off = LCAP;
        int nq8 = (off + 7) & ~7;       // LCAP is a mult of 8 -> nq8 <= LCAP
        if (off + lane < nq8) dst[off + lane] = make_float4(0.f, 0.f, 0.f, DUMMYW);
        if (lane == 0) nqCL[u] = nq8;
    }
}

// Node 4: block = (b,cell), 4 waves. Every wave holds the SAME R=3 dom tile;
// the contiguous padded q-list is SPLIT across the 4 waves (theta_b is linear
// in q-contributions) -> 8000 waves (r9 had 2000 = 1/SIMD, 51% VALUBusy issue-
// starved). Partial theta_b reduced across waves in LDS, multiplied by TC,
// block reduce, one atomic + vmcnt-ordered ticket (r7-r9 proven).
__global__ void __launch_bounds__(256) k_main(const float4* __restrict__ PDbin,
                                              const float4* __restrict__ CL,
                                              const float* __restrict__ TC,
                                              int* __restrict__ cnts,
                                              float* __restrict__ out) {
    const int* cntD = cnts + W_CNTD;
    const int* nqCL = cnts + W_NQCL;
    float* prod = (float*)(cnts + W_PROD);
    unsigned* done = (unsigned*)(cnts + W_DONE);

    __shared__ float part[4 * DOMCAP];
    __shared__ float wsum[4];
    __shared__ int fin;

    int tid = threadIdx.x;
    int lane = tid & 63, w = tid >> 6;
    int b = blockIdx.x / NCELL, cell = blockIdx.x - b * NCELL;
    int nbhd = (cell / 25) * NC + (cell / 5) % 5;   // cx*5+cy

    // R=3 dom register tile (same for all 4 waves; sanitize dead lanes)
    int len = __builtin_amdgcn_readfirstlane(min(cntD[cell], DOMCAP));
    const float4* __restrict__ PD = PDbin + cell * DOMCAP;
    float4 d0 = make_float4(0.f, 0.f, 0.f, 0.f);
    float4 d1 = d0, d2 = d0;
    if (lane < len)       d0 = PD[lane];
    if (lane + 64 < len)  d1 = PD[lane + 64];
    if (lane + 128 < len) d2 = PD[lane + 128];

    // this wave's q-share of the contiguous padded list (shares on x8 bounds)
    int nq8 = __builtin_amdgcn_readfirstlane(nqCL[b * NCOL + nbhd]);   // mult of 8
    int sh = (((nq8 >> 3) + 3) >> 2) << 3;          // per-wave share, mult of 8
    int q0 = w * sh;
    int q1 = min(q0 + sh, nq8);
    const float4* __restrict__ p = CL + (size_t)(b * NCOL + nbhd) * LCAP;

    float s0 = 0.f, s1 = 0.f, s2 = 0.f;
    #pragma unroll 1
    for (int i = q0; i < q1; i += 8) BODY8(p, i);

    part[w * DOMCAP + lane]       = s0;
    part[w * DOMCAP + lane + 64]  = s1;
    part[w * DOMCAP + lane + 128] = s2;
    __syncthreads();

    float v = 0.f;
    if (tid < DOMCAP) {
        float tb = part[tid] + part[DOMCAP + tid] + part[2 * DOMCAP + tid]
                 + part[3 * DOMCAP + tid];
        // select, not multiply: dead-slot TC may be poison; NaN never passes select
        v = (tid < len) ? tb * TC[cell * DOMCAP + tid] : 0.f;
    }
    for (int o = 32; o; o >>= 1) v += __shfl_down(v, o, 64);
    if (lane == 0) wsum[w] = v;
    __syncthreads();
    if (tid == 0) {
        atomicAdd(prod + b, wsum[0] + wsum[1] + wsum[2] + wsum[3]);
        asm volatile("s_waitcnt vmcnt(0)" ::: "memory");   // prod add performed
        unsigned old = atomicAdd(done, 1u);
        fin = (old == (unsigned)(MAIN_BLOCKS - 1)) ? 1 : 0;
    }
    __syncthreads();
    if (fin && tid < 16) {
        const float scale = 4.76837158203125e-4f;  // A*V/1024
        float ptot = atomicAdd(prod + tid, 0.0f);  // coherent read
        float dot = fminf(fmaxf(ptot * scale, 0.0f), 1.0f);
        out[tid] = 1.0f - dot;
    }
}

extern "C" void kernel_launch(void* const* d_in, const int* in_sizes, int n_in,
                              void* d_out, int out_size, void* d_ws, size_t ws_size,
                              hipStream_t stream) {
    const float* C1  = (const float*)d_in[0];   // (16,1024,3)
    const float* C   = (const float*)d_in[1];   // (1024,3)
    const float* dom = (const float*)d_in[2];   // (16384,3)
    float* out = (float*)d_out;                 // (16,)

    char* ws = (char*)d_ws;
    float4* PDbin = (float4*)(ws + 0);          // 125*192*16   =   384000
    float4* C1col = (float4*)(ws + 384000);     // 16*25*96*16  =   614400 ->  998400
    float4* Ccol  = (float4*)(ws + 998400);     // 25*96*16     =    38400 -> 1036800
    float*  TC    = (float*)(ws + 1036800);     // 125*192*4    =    96000 -> 1132800
    float4* CL    = (float4*)(ws + 1132800);    // 400*576*16   =  3686400 -> 4819200
    int*    cnts  = (int*)(ws + 4819200);       // 967 words    -> ~4.82MB total

    hipMemsetAsync(cnts, 0, W_TOTAL * 4, stream);
    k_bin<<<GRID_BIN, 256, 0, stream>>>(C1, C, dom, PDbin, C1col, Ccol, cnts);
    k_tc<<<775, 64, 0, stream>>>(PDbin, C1col, Ccol, CL, TC, cnts);
    k_main<<<MAIN_BLOCKS, 256, 0, stream>>>(PDbin, CL, TC, cnts, out);
}

// Round 11
// 124.970 us; speedup vs baseline: 1.1267x; 1.0829x over previous
//
#include <hip/hip_runtime.h>
#include <math.h>

// L = 2*pi * log2(e): exp(-2pi r^2) == exp2(-L r^2)
#define LCONST 9.064720283654388f

// dom binned into 5x5x5 cells (size 2.0) over [0,10)^3; C1/C binned by (x,y)
// COLUMN only (25 columns). A cell's neighborhood = <=9 columns; the missing
// z-filter is free because out-of-cutoff pairs underflow exp2 to 0.
// Cutoff r=2: dropped terms ~1.2e-11 vs theta ~0.36 -> below f32 ulp: exact.
#define NC 5
#define NCELL 125
#define NCOL 25
#define DOMCAP 192   // dom/cell: mean 131, sigma 11.4 -> +5.3 sigma (r2-r10 passed)
#define COLCAP 96    // pts/(b,col): mean 41, sigma 6.4 -> +8.6 sigma
#define NB 16
#define GRID_BIN 132              // 132*256 = 33792 = exactly all points to bin
#define MAIN_BLOCKS (NB * NCELL)  // 2000 blocks x 4 waves = 8000 waves
#define LCAP 576     // packed nbhd list cap: mean ~369, sigma ~15 -> +13 sigma; x8
#define DUMMYW -1.0e30f  // pad w: arg <= -1e30 -> exp2 = 0 exactly, no NaN path

// cnts word layout (memset-zeroed each run)
#define W_CNTD 0      // 125
#define W_CNTC1 125   // 400
#define W_CNTC 525    // 25
#define W_PROD 550    // 16 floats
#define W_DONE 566    // block ticket
#define W_TOTAL 567

__device__ __forceinline__ float fexp2(float x) {
#if defined(__has_builtin)
#if __has_builtin(__builtin_amdgcn_exp2f)
    return __builtin_amdgcn_exp2f(x);
#else
    return exp2f(x);
#endif
#else
    return exp2f(x);
#endif
}

__device__ __forceinline__ int clamp5(float v) {
    int c = (int)(v * 0.5f);
    return c < 0 ? 0 : (c > NC - 1 ? NC - 1 : c);
}

// Full exponent arg = -L||d-q||^2 <= 0 stays in ONE exp2 argument (factoring
// exp2(d.w) out overflows: inf*0=NaN -- round-1 bug).
#define PAIR_ARG(d, q) fmaf((d).x, (q).x, fmaf((d).y, (q).y, fmaf((d).z, (q).z, (d).w + (q).w)))

// R=3 register tile: one broadcast ds_read_b128 feeds 192 pairs (64 lanes x 3
// dom points). LDS pipe ~96cyc/BODY8 vs ~432 VALU-cyc -> VALU-bound (r8 was
// LDS-bound only because R=1 put 1 read per 64 pairs).
#define EVAL3(qq) do { \
    s0 += fexp2(PAIR_ARG(d0, qq)); \
    s1 += fexp2(PAIR_ARG(d1, qq)); \
    s2 += fexp2(PAIR_ARG(d2, qq)); } while (0)

#define BODY8(P, I) do { \
    float4 q0 = (P)[(I)],     q1 = (P)[(I) + 1], q2 = (P)[(I) + 2], q3 = (P)[(I) + 3]; \
    float4 q4 = (P)[(I) + 4], q5 = (P)[(I) + 5], q6 = (P)[(I) + 6], q7 = (P)[(I) + 7]; \
    EVAL3(q0); EVAL3(q1); EVAL3(q2); EVAL3(q3); \
    EVAL3(q4); EVAL3(q5); EVAL3(q6); EVAL3(q7); } while (0)

// Stage the <=9 neighbor columns into ONE packed LDS list, pad to x8 with
// exp2->0 dummies. 256 threads, one coalesced pass per column (n <= 96).
// Clamped reads never touch poisoned slots >= cnt; drop-clamp at LCAP can't
// OOB. Returns padded length (uniform). Ends with __syncthreads.
__device__ __forceinline__ int stage_nbhd(int cx, int cy,
                                          const float4* __restrict__ cols,
                                          const int* __restrict__ cnt,
                                          float4* slq, int tid) {
    int xlo = cx > 0 ? cx - 1 : 0, xhi = cx < NC - 1 ? cx + 1 : NC - 1;
    int ylo = cy > 0 ? cy - 1 : 0, yhi = cy < NC - 1 ? cy + 1 : NC - 1;
    int off = 0;
    #pragma unroll 1
    for (int x2 = xlo; x2 <= xhi; ++x2) {
        #pragma unroll 1
        for (int y2 = ylo; y2 <= yhi; ++y2) {
            int col = x2 * NC + y2;
            int n = min(cnt[col], COLCAP);          // uniform scalar
            if (tid < n && off + tid < LCAP)
                slq[off + tid] = cols[(size_t)col * COLCAP + tid];
            off += n;
        }
    }
    if (off > LCAP) off = LCAP;
    int nq8 = (off + 7) & ~7;                       // LCAP mult of 8 -> <= LCAP
    if (tid < nq8 - off) slq[off + tid] = make_float4(0.f, 0.f, 0.f, DUMMYW);
    __syncthreads();
    return nq8;
}

// Node 2: pure binning, global atomics, no fences (r7-proven).
__global__ void __launch_bounds__(256) k_bin(const float* __restrict__ C1,
                                             const float* __restrict__ C,
                                             const float* __restrict__ dom,
                                             float4* __restrict__ PDbin,
                                             float4* __restrict__ C1col,
                                             float4* __restrict__ Ccol,
                                             int* __restrict__ cnts) {
    int* cntD  = cnts + W_CNTD;
    int* cntC1 = cnts + W_CNTC1;
    int* cntC  = cnts + W_CNTC;
    int t = blockIdx.x * 256 + threadIdx.x;   // 0..33791 exactly
    if (t < 16384) {
        float x = dom[3 * t], y = dom[3 * t + 1], z = dom[3 * t + 2];
        int cell = (clamp5(x) * NC + clamp5(y)) * NC + clamp5(z);
        int s = atomicAdd(cntD + cell, 1);
        if (s < DOMCAP)   // clamp: overflowed bins can't OOB
            PDbin[cell * DOMCAP + s] =
                make_float4(2.0f * LCONST * x, 2.0f * LCONST * y, 2.0f * LCONST * z,
                            -LCONST * (x * x + y * y + z * z));
    } else if (t < 32768) {
        int j = t - 16384;
        float x = C1[3 * j], y = C1[3 * j + 1], z = C1[3 * j + 2];
        int b = j >> 10;
        int col = clamp5(x) * NC + clamp5(y);
        int s = atomicAdd(cntC1 + b * NCOL + col, 1);
        if (s < COLCAP)
            C1col[(b * NCOL + col) * COLCAP + s] =
                make_float4(x, y, z, -LCONST * (x * x + y * y + z * z));
    } else {
        int j = t - 32768;
        float x = C[3 * j], y = C[3 * j + 1], z = C[3 * j + 2];
        int col = clamp5(x) * NC + clamp5(y);
        int s = atomicAdd(cntC + col, 1);
        if (s < COLCAP)
            Ccol[col * COLCAP + s] =
                make_float4(x, y, z, -LCONST * (x * x + y * y + z * z));
    }
}

// Node 3: TC[slot] = theta_C per dom slot. One block per cell, 256 threads:
// stage C-nbhd into LDS, 4 waves split the q-range (theta linear in q), R=3,
// cross-wave LDS reduce, write per-slot (finite for ALL 192 slots; dead slots
// masked by select in k_main).
__global__ void __launch_bounds__(256) k_tc(const float4* __restrict__ PDbin,
                                            const float4* __restrict__ Ccol,
                                            float* __restrict__ TC,
                                            const int* __restrict__ cnts) {
    const int* cntD = cnts + W_CNTD;
    const int* cntC = cnts + W_CNTC;
    __shared__ float4 slq[LCAP];
    __shared__ float part[4 * DOMCAP];

    int tid = threadIdx.x, lane = tid & 63, w = tid >> 6;
    int cell = blockIdx.x;
    int cx = cell / 25, cy = (cell / 5) % 5;

    int len = min(cntD[cell], DOMCAP);              // uniform scalar
    const float4* __restrict__ PD = PDbin + cell * DOMCAP;
    float4 d0 = make_float4(0.f, 0.f, 0.f, 0.f);    // sanitize poison lanes
    float4 d1 = d0, d2 = d0;
    if (lane < len)       d0 = PD[lane];
    if (lane + 64 < len)  d1 = PD[lane + 64];
    if (lane + 128 < len) d2 = PD[lane + 128];

    int nq8 = stage_nbhd(cx, cy, Ccol, cntC, slq, tid);
    int sh = (((nq8 >> 3) + 3) >> 2) << 3;          // per-wave share, mult of 8
    int q0 = w * sh, q1 = min(q0 + sh, nq8);

    float s0 = 0.f, s1 = 0.f, s2 = 0.f;
    #pragma unroll 1
    for (int i = q0; i < q1; i += 8) BODY8(slq, i);

    part[w * DOMCAP + lane]       = s0;
    part[w * DOMCAP + lane + 64]  = s1;
    part[w * DOMCAP + lane + 128] = s2;
    __syncthreads();
    if (tid < DOMCAP)
        TC[cell * DOMCAP + tid] = part[tid] + part[DOMCAP + tid]
                                + part[2 * DOMCAP + tid] + part[3 * DOMCAP + tid];
}

// Node 4: block = (b,cell), 4 waves. Stage the (b,nbhd) C1 columns into LDS
// (deletes r10's global CL array + builder: its wave-uniform GLOBAL q-loads
// were the 60% issue-stall -- FETCH 5.7MB, L2-cold across XCDs). All waves
// hold the same R=3 dom tile; q-range split 4 ways; part-reduce; x TC;
// one atomic + vmcnt-ordered ticket (r7-r10 proven).
__global__ void __launch_bounds__(256) k_main(const float4* __restrict__ PDbin,
                                              const float4* __restrict__ C1col,
                                              const float* __restrict__ TC,
                                              int* __restrict__ cnts,
                                              float* __restrict__ out) {
    const int* cntD  = cnts + W_CNTD;
    const int* cntC1 = cnts + W_CNTC1;
    float* prod = (float*)(cnts + W_PROD);
    unsigned* done = (unsigned*)(cnts + W_DONE);

    __shared__ float4 slq[LCAP];
    __shared__ float part[4 * DOMCAP];
    __shared__ float wsum[4];
    __shared__ int fin;

    int tid = threadIdx.x, lane = tid & 63, w = tid >> 6;
    int b = blockIdx.x / NCELL, cell = blockIdx.x - b * NCELL;
    int cx = cell / 25, cy = (cell / 5) % 5;

    int len = min(cntD[cell], DOMCAP);              // uniform scalar
    const float4* __restrict__ PD = PDbin + cell * DOMCAP;
    float4 d0 = make_float4(0.f, 0.f, 0.f, 0.f);    // sanitize poison lanes
    float4 d1 = d0, d2 = d0;
    if (lane < len)       d0 = PD[lane];
    if (lane + 64 < len)  d1 = PD[lane + 64];
    if (lane + 128 < len) d2 = PD[lane + 128];

    int nq8 = stage_nbhd(cx, cy, C1col + (size_t)b * (NCOL * COLCAP),
                         cntC1 + b * NCOL, slq, tid);
    int sh = (((nq8 >> 3) + 3) >> 2) << 3;          // per-wave share, mult of 8
    int q0 = w * sh, q1 = min(q0 + sh, nq8);

    float s0 = 0.f, s1 = 0.f, s2 = 0.f;
    #pragma unroll 1
    for (int i = q0; i < q1; i += 8) BODY8(slq, i);

    part[w * DOMCAP + lane]       = s0;
    part[w * DOMCAP + lane + 64]  = s1;
    part[w * DOMCAP + lane + 128] = s2;
    __syncthreads();

    float v = 0.f;
    if (tid < DOMCAP) {
        float tb = part[tid] + part[DOMCAP + tid] + part[2 * DOMCAP + tid]
                 + part[3 * DOMCAP + tid];
        // select, not multiply: dead-slot TC is finite-garbage; NaN never passes
        v = (tid < len) ? tb * TC[cell * DOMCAP + tid] : 0.f;
    }
    for (int o = 32; o; o >>= 1) v += __shfl_down(v, o, 64);
    if (lane == 0) wsum[w] = v;
    __syncthreads();
    if (tid == 0) {
        atomicAdd(prod + b, wsum[0] + wsum[1] + wsum[2] + wsum[3]);
        asm volatile("s_waitcnt vmcnt(0)" ::: "memory");   // prod add performed
        unsigned old = atomicAdd(done, 1u);
        fin = (old == (unsigned)(MAIN_BLOCKS - 1)) ? 1 : 0;
    }
    __syncthreads();
    if (fin && tid < 16) {
        const float scale = 4.76837158203125e-4f;  // A*V/1024
        float ptot = atomicAdd(prod + tid, 0.0f);  // coherent read
        float dot = fminf(fmaxf(ptot * scale, 0.0f), 1.0f);
        out[tid] = 1.0f - dot;
    }
}

extern "C" void kernel_launch(void* const* d_in, const int* in_sizes, int n_in,
                              void* d_out, int out_size, void* d_ws, size_t ws_size,
                              hipStream_t stream) {
    const float* C1  = (const float*)d_in[0];   // (16,1024,3)
    const float* C   = (const float*)d_in[1];   // (1024,3)
    const float* dom = (const float*)d_in[2];   // (16384,3)
    float* out = (float*)d_out;                 // (16,)

    char* ws = (char*)d_ws;
    float4* PDbin = (float4*)(ws + 0);          // 125*192*16   =   384000
    float4* C1col = (float4*)(ws + 384000);     // 16*25*96*16  =   614400 ->  998400
    float4* Ccol  = (float4*)(ws + 998400);     // 25*96*16     =    38400 -> 1036800
    float*  TC    = (float*)(ws + 1036800);     // 125*192*4    =    96000 -> 1132800
    int*    cnts  = (int*)(ws + 1132800);       // 567 words    -> ~1.13MB total

    hipMemsetAsync(cnts, 0, W_TOTAL * 4, stream);
    k_bin<<<GRID_BIN, 256, 0, stream>>>(C1, C, dom, PDbin, C1col, Ccol, cnts);
    k_tc<<<NCELL, 256, 0, stream>>>(PDbin, Ccol, TC, cnts);
    k_main<<<MAIN_BLOCKS, 256, 0, stream>>>(PDbin, C1col, TC, cnts, out);
}